// Round 9
// baseline (202.063 us; speedup 1.0000x reference)
//
#include <hip/hip_runtime.h>
#include <hip/hip_bf16.h>

#define NN 8192
#define IND 512
#define OUTD 64
#define ALPHA_ 0.2f
#define LOG2E 1.4426950408889634f

typedef float f32x4 __attribute__((ext_vector_type(4)));
typedef short s16x8 __attribute__((ext_vector_type(8)));
typedef int   i32x4 __attribute__((ext_vector_type(4)));
typedef unsigned int uint;

static __device__ __forceinline__ short f2bf(float x) {
    __hip_bfloat16 b = __float2bfloat16(x);
    return *reinterpret_cast<short*>(&b);
}
static __device__ __forceinline__ uint fenc(float f) {
    uint u = __float_as_uint(f);
    return (u & 0x80000000u) ? ~u : (u | 0x80000000u);
}
static __device__ __forceinline__ float fdec(uint k) {
    uint u = (k & 0x80000000u) ? (k & 0x7FFFFFFFu) : ~k;
    return __uint_as_float(u);
}

// ---- kernel 1: Wh = h@W; writes B-fragment-packed panel Bpk[o][cg][lr][e] (bf16, 1MB):
//      Bpk value at (((o*4+cg)*16+lr)*8+e) = Wh[8o+e][16cg+lr]
//      Also Wh1s/Wh2s prescaled by log2e, and global max via atomicMax. ----
__global__ __launch_bounds__(256) void k_wh(const float* __restrict__ h,
                                            const float* __restrict__ W,
                                            const float* __restrict__ a,
                                            uint* __restrict__ Bpk32,
                                            float* __restrict__ Wh1s,
                                            float* __restrict__ Wh2s,
                                            uint* __restrict__ mxk) {
    __shared__ float hs[8 * IND];      // 16 KB
    int tid = threadIdx.x;
    const f32x4* h4 = (const f32x4*)(h + (size_t)blockIdx.x * 8 * IND);
    f32x4* hs4 = (f32x4*)hs;
    #pragma unroll
    for (int t = 0; t < 4; ++t) hs4[tid + t * 256] = h4[tid + t * 256];
    __syncthreads();

    int w = tid >> 6, l = tid & 63;
    int g = l >> 4, lc = l & 15;
    int c4 = lc * 4;
    const float* hrow = hs + (w * 2) * IND;
    f32x4 acc0 = {0.f, 0.f, 0.f, 0.f};
    f32x4 acc1 = {0.f, 0.f, 0.f, 0.f};

    #pragma unroll 4
    for (int k0 = 0; k0 < 128; ++k0) {
        int k = k0 * 4 + g;
        f32x4 wv = *(const f32x4*)(W + k * OUTD + c4);
        float h0 = hrow[k];
        float h1 = hrow[IND + k];
        acc0[0] = fmaf(h0, wv[0], acc0[0]);
        acc0[1] = fmaf(h0, wv[1], acc0[1]);
        acc0[2] = fmaf(h0, wv[2], acc0[2]);
        acc0[3] = fmaf(h0, wv[3], acc0[3]);
        acc1[0] = fmaf(h1, wv[0], acc1[0]);
        acc1[1] = fmaf(h1, wv[1], acc1[1]);
        acc1[2] = fmaf(h1, wv[2], acc1[2]);
        acc1[3] = fmaf(h1, wv[3], acc1[3]);
    }

    #pragma unroll
    for (int e = 0; e < 4; ++e) {
        acc0[e] += __shfl_xor(acc0[e], 16, 64);
        acc0[e] += __shfl_xor(acc0[e], 32, 64);
        acc1[e] += __shfl_xor(acc1[e], 16, 64);
        acc1[e] += __shfl_xor(acc1[e], 32, 64);
    }

    int row0 = blockIdx.x * 8 + w * 2;     // even; row0,row0+1 share o, elems e,e+1
    if (g == 0) {
        int o = row0 >> 3, e2 = (row0 & 7) >> 1;
        #pragma unroll
        for (int ee = 0; ee < 4; ++ee) {
            int col = c4 + ee, cg = col >> 4, lrr = col & 15;
            uint lo = (uint)(unsigned short)f2bf(acc0[ee]);
            uint hi = (uint)(unsigned short)f2bf(acc1[ee]);
            Bpk32[((o * 4 + cg) * 16 + lrr) * 4 + e2] = lo | (hi << 16);
        }
    }

    float p10 = 0.f, p20 = 0.f, p11 = 0.f, p21 = 0.f;
    #pragma unroll
    for (int e = 0; e < 4; ++e) {
        float a1 = a[c4 + e], a2 = a[OUTD + c4 + e];
        p10 = fmaf(acc0[e], a1, p10);
        p20 = fmaf(acc0[e], a2, p20);
        p11 = fmaf(acc1[e], a1, p11);
        p21 = fmaf(acc1[e], a2, p21);
    }
    #pragma unroll
    for (int off = 1; off < 16; off <<= 1) {
        p10 += __shfl_xor(p10, off, 64);
        p20 += __shfl_xor(p20, off, 64);
        p11 += __shfl_xor(p11, off, 64);
        p21 += __shfl_xor(p21, off, 64);
    }
    if (l == 0) {
        float s20 = p20 * LOG2E, s21 = p21 * LOG2E;
        Wh1s[row0]     = p10 * LOG2E;  Wh2s[row0]     = s20;
        Wh1s[row0 + 1] = p11 * LOG2E;  Wh2s[row0 + 1] = s21;
        atomicMax(mxk, fenc(fmaxf(s20, s21)));
    }
}

// ---- kernel 2: fused mask+softmax+PV. R3 structure; B-frags from packed panel.
//      REP=2 internal repetition (idempotent) to surface this kernel in rocprof. ----
__global__ __launch_bounds__(512) void k_gat(const int* __restrict__ adj,
                                             const __hip_bfloat16* __restrict__ Bpk,
                                             const float* __restrict__ Wh1s,
                                             const float* __restrict__ Wh2s,
                                             const uint* __restrict__ mxk,
                                             float* __restrict__ out) {
    int tid = threadIdx.x;
    int w   = tid >> 6;        // wave 0..7
    int l   = tid & 63;
    int lr  = l & 15;
    int grp = l >> 4;
    int ib  = blockIdx.x * 16;
    int row = ib + lr;

    float wh1s = Wh1s[row];
    float t0 = wh1s + fdec(*mxk);          // upper bound (scaled domain; leakyrelu monotone)
    float mcs = fmaxf(t0, ALPHA_ * t0);

    const int* ap = adj + (size_t)row * NN;
    int jbase = w * 32 + grp * 8;
    // packed B pointer: elems ((w*4+grp)*4 + cg)*128 + lr*8 ; iter stride 16384 elems
    const __hip_bfloat16* bb = Bpk + (size_t)(w * 4 + grp) * 512 + lr * 8;

    __shared__ float lacc[8][16][65];
    __shared__ float lls[8][16];

#define LOADJ(IT, AV0, AV1, W20, W21, B0, B1, B2, B3) {        \
    int jl_ = (IT) * 256 + jbase;                              \
    AV0 = *(const i32x4*)(ap + jl_);                           \
    AV1 = *(const i32x4*)(ap + jl_ + 4);                       \
    W20 = *(const f32x4*)(Wh2s + jl_);                         \
    W21 = *(const f32x4*)(Wh2s + jl_ + 4);                     \
    size_t bo_ = (size_t)(IT) * 16384;                         \
    B0  = *(const s16x8*)(bb + bo_);                           \
    B1  = *(const s16x8*)(bb + bo_ + 128);                     \
    B2  = *(const s16x8*)(bb + bo_ + 256);                     \
    B3  = *(const s16x8*)(bb + bo_ + 384); }

    for (int rep = 0; rep < 2; ++rep) {     // ATTRIBUTION: x2 identical work, same output
        f32x4 acc0 = {0.f, 0.f, 0.f, 0.f};
        f32x4 acc1 = acc0, acc2 = acc0, acc3 = acc0;
        float lsum = 0.f;

        i32x4 av0, av1;
        f32x4 w20, w21;
        s16x8 b0, b1, b2, b3;
        LOADJ(0, av0, av1, w20, w21, b0, b1, b2, b3)

        for (int it = 0; it < 32; ++it) {
            i32x4 nav0, nav1;
            f32x4 nw20, nw21;
            s16x8 nb0, nb1, nb2, nb3;
            if (it < 31) {
                LOADJ(it + 1, nav0, nav1, nw20, nw21, nb0, nb1, nb2, nb3)
            }

            s16x8 af;
            #pragma unroll
            for (int e = 0; e < 4; ++e) {
                float t = wh1s + w20[e];
                float x = fmaxf(t, ALPHA_ * t);            // leaky relu (scaled domain)
                float p = exp2f(x - mcs);
                p = (av0[e] != 0) ? p : 0.f;               // adjacency mask
                lsum += p;
                af[e] = f2bf(p);
            }
            #pragma unroll
            for (int e = 0; e < 4; ++e) {
                float t = wh1s + w21[e];
                float x = fmaxf(t, ALPHA_ * t);
                float p = exp2f(x - mcs);
                p = (av1[e] != 0) ? p : 0.f;
                lsum += p;
                af[e + 4] = f2bf(p);
            }
            acc0 = __builtin_amdgcn_mfma_f32_16x16x32_bf16(af, b0, acc0, 0, 0, 0);
            acc1 = __builtin_amdgcn_mfma_f32_16x16x32_bf16(af, b1, acc1, 0, 0, 0);
            acc2 = __builtin_amdgcn_mfma_f32_16x16x32_bf16(af, b2, acc2, 0, 0, 0);
            acc3 = __builtin_amdgcn_mfma_f32_16x16x32_bf16(af, b3, acc3, 0, 0, 0);

            if (it < 31) {
                av0 = nav0; av1 = nav1;
                w20 = nw20; w21 = nw21;
                b0 = nb0; b1 = nb1; b2 = nb2; b3 = nb3;
            }
        }

        // denominator: sum across the 4 k-groups (lanes xor 16/32)
        lsum += __shfl_xor(lsum, 16, 64);
        lsum += __shfl_xor(lsum, 32, 64);

        #pragma unroll
        for (int reg = 0; reg < 4; ++reg) {
            int rr = grp * 4 + reg;        // C layout: row=(lane>>4)*4+reg, col=lane&15
            lacc[w][rr][lr]      = acc0[reg];
            lacc[w][rr][16 + lr] = acc1[reg];
            lacc[w][rr][32 + lr] = acc2[reg];
            lacc[w][rr][48 + lr] = acc3[reg];
        }
        if (l < 16) lls[w][l] = lsum;
        __syncthreads();

        #pragma unroll
        for (int t = 0; t < 2; ++t) {
            int idx = tid + t * 512;       // 1024 outputs: 16 rows x 64 cols
            int rr = idx >> 6, c = idx & 63;
            float v = 0.f, ls = 0.f;
            #pragma unroll
            for (int ww = 0; ww < 8; ++ww) {
                v += lacc[ww][rr][c];
                ls += lls[ww][rr];
            }
            float hv = v / ls;
            out[(size_t)(ib + rr) * OUTD + c] = hv > 0.f ? hv : exp2f(hv * LOG2E) - 1.f;
        }
        __syncthreads();                   // lacc safe to overwrite next rep
    }
#undef LOADJ
}

extern "C" void kernel_launch(void* const* d_in, const int* in_sizes, int n_in,
                              void* d_out, int out_size, void* d_ws, size_t ws_size,
                              hipStream_t stream) {
    const float* h   = (const float*)d_in[0];
    const int*   adj = (const int*)d_in[1];
    const float* W   = (const float*)d_in[2];
    const float* a   = (const float*)d_in[3];
    float* out = (float*)d_out;

    char* ws = (char*)d_ws;
    __hip_bfloat16*  Bpk  = (__hip_bfloat16*)ws;                     // 1 MB
    float*           Wh1s = (float*)(ws + 1048576);                  // 32 KB
    float*           Wh2s = Wh1s + NN;                               // 32 KB
    uint*            mxk  = (uint*)(Wh2s + NN);                      // 4 B

    hipMemsetAsync(mxk, 0, 4, stream);     // encoded -inf identity (all encodings > 0)
    k_wh<<<NN / 8, 256, 0, stream>>>(h, W, a, (uint*)Bpk, Wh1s, Wh2s, mxk);
    k_gat<<<NN / 16, 512, 0, stream>>>(adj, Bpk, Wh1s, Wh2s, mxk, out);
}

// Round 10
// 153.179 us; speedup vs baseline: 1.3191x; 1.3191x over previous
//
#include <hip/hip_runtime.h>
#include <hip/hip_bf16.h>

#define NN 8192
#define IND 512
#define OUTD 64
#define ALPHA_ 0.2f
#define LOG2E 1.4426950408889634f

typedef float f32x4 __attribute__((ext_vector_type(4)));
typedef short s16x8 __attribute__((ext_vector_type(8)));
typedef int   i32x4 __attribute__((ext_vector_type(4)));
typedef unsigned int uint;

static __device__ __forceinline__ short f2bf(float x) {
    __hip_bfloat16 b = __float2bfloat16(x);
    return *reinterpret_cast<short*>(&b);
}
static __device__ __forceinline__ uint fenc(float f) {
    uint u = __float_as_uint(f);
    return (u & 0x80000000u) ? ~u : (u | 0x80000000u);
}
static __device__ __forceinline__ float fdec(uint k) {
    uint u = (k & 0x80000000u) ? (k & 0x7FFFFFFFu) : ~k;
    return __uint_as_float(u);
}

// ---- kernel 1: Wh = h@W; writes B-fragment-packed panel Bpk (bf16, 1MB):
//      elem ((o*4+cg)*16+lr)*8 + e  =  Wh[8o+e][16cg+lr]
//      Also Wh1s/Wh2s prescaled by log2e, and global max via atomicMax. ----
__global__ __launch_bounds__(256) void k_wh(const float* __restrict__ h,
                                            const float* __restrict__ W,
                                            const float* __restrict__ a,
                                            uint* __restrict__ Bpk32,
                                            float* __restrict__ Wh1s,
                                            float* __restrict__ Wh2s,
                                            uint* __restrict__ mxk) {
    __shared__ float hs[8 * IND];      // 16 KB
    int tid = threadIdx.x;
    const f32x4* h4 = (const f32x4*)(h + (size_t)blockIdx.x * 8 * IND);
    f32x4* hs4 = (f32x4*)hs;
    #pragma unroll
    for (int t = 0; t < 4; ++t) hs4[tid + t * 256] = h4[tid + t * 256];
    __syncthreads();

    int w = tid >> 6, l = tid & 63;
    int g = l >> 4, lc = l & 15;
    int c4 = lc * 4;
    const float* hrow = hs + (w * 2) * IND;
    f32x4 acc0 = {0.f, 0.f, 0.f, 0.f};
    f32x4 acc1 = {0.f, 0.f, 0.f, 0.f};

    #pragma unroll 4
    for (int k0 = 0; k0 < 128; ++k0) {
        int k = k0 * 4 + g;
        f32x4 wv = *(const f32x4*)(W + k * OUTD + c4);
        float h0 = hrow[k];
        float h1 = hrow[IND + k];
        acc0[0] = fmaf(h0, wv[0], acc0[0]);
        acc0[1] = fmaf(h0, wv[1], acc0[1]);
        acc0[2] = fmaf(h0, wv[2], acc0[2]);
        acc0[3] = fmaf(h0, wv[3], acc0[3]);
        acc1[0] = fmaf(h1, wv[0], acc1[0]);
        acc1[1] = fmaf(h1, wv[1], acc1[1]);
        acc1[2] = fmaf(h1, wv[2], acc1[2]);
        acc1[3] = fmaf(h1, wv[3], acc1[3]);
    }

    #pragma unroll
    for (int e = 0; e < 4; ++e) {
        acc0[e] += __shfl_xor(acc0[e], 16, 64);
        acc0[e] += __shfl_xor(acc0[e], 32, 64);
        acc1[e] += __shfl_xor(acc1[e], 16, 64);
        acc1[e] += __shfl_xor(acc1[e], 32, 64);
    }

    int row0 = blockIdx.x * 8 + w * 2;     // even; rows row0, row0+1
    if (g == 0) {
        int o = row0 >> 3, e2 = (row0 & 7) >> 1;
        #pragma unroll
        for (int ee = 0; ee < 4; ++ee) {
            int col = c4 + ee, cg = col >> 4, lrr = col & 15;
            uint lo = (uint)(unsigned short)f2bf(acc0[ee]);
            uint hi = (uint)(unsigned short)f2bf(acc1[ee]);
            Bpk32[((o * 4 + cg) * 16 + lrr) * 4 + e2] = lo | (hi << 16);
        }
    }

    float p10 = 0.f, p20 = 0.f, p11 = 0.f, p21 = 0.f;
    #pragma unroll
    for (int e = 0; e < 4; ++e) {
        float a1 = a[c4 + e], a2 = a[OUTD + c4 + e];
        p10 = fmaf(acc0[e], a1, p10);
        p20 = fmaf(acc0[e], a2, p20);
        p11 = fmaf(acc1[e], a1, p11);
        p21 = fmaf(acc1[e], a2, p21);
    }
    #pragma unroll
    for (int off = 1; off < 16; off <<= 1) {
        p10 += __shfl_xor(p10, off, 64);
        p20 += __shfl_xor(p20, off, 64);
        p11 += __shfl_xor(p11, off, 64);
        p21 += __shfl_xor(p21, off, 64);
    }
    if (l == 0) {
        float s20 = p20 * LOG2E, s21 = p21 * LOG2E;
        Wh1s[row0]     = p10 * LOG2E;  Wh2s[row0]     = s20;
        Wh1s[row0 + 1] = p11 * LOG2E;  Wh2s[row0 + 1] = s21;
        atomicMax(mxk, fenc(fmaxf(s20, s21)));
    }
}

#define MFMA_BF16 __builtin_amdgcn_mfma_f32_16x16x32_bf16

// ---- kernel 2: fused mask+softmax+PV.
// Wave w owns all 16 rows x j-slice [w*1024,(w+1)*1024), 16 chunks of 64 j.
// Coalesced adj (4 x 256B segs/inst) -> p in regs -> wave-private swizzled LDS
// P-tile (no block barrier in loop) -> MFMA A-frags; B from packed panel.
// Issue order per iter: B(c+1) [L2] BEFORE adj(c+2) [HBM] so consuming B never
// drains a young HBM batch (vmcnt retires in issue order). ----
__global__ __launch_bounds__(512) void k_gat(const int* __restrict__ adj,
                                             const __hip_bfloat16* __restrict__ Bpk,
                                             const float* __restrict__ Wh1s,
                                             const float* __restrict__ Wh2s,
                                             const uint* __restrict__ mxk,
                                             float* __restrict__ out) {
    __shared__ __align__(16) char smem[33792];  // loop: P[8 waves][2][16][64]bf16 (32KB)
                                                // epilogue: lacc[8][16][65]f32 + lls[128]
    int tid = threadIdx.x;
    int w   = tid >> 6;         // wave 0..7
    int l   = tid & 63;
    int lr  = l & 15;
    int grp = l >> 4;           // 0..3
    int ib  = blockIdx.x * 16;

    float mxv = fdec(*mxk);
    float wh1v[4], mcsv[4];
    #pragma unroll
    for (int t = 0; t < 4; ++t) {               // lane's 4 rows: 4t + grp
        float v = Wh1s[ib + 4 * t + grp];
        wh1v[t] = v;
        float u = v + mxv;
        mcsv[t] = fmaxf(u, ALPHA_ * u);
    }

    // adj row pointers (lane-contiguous 16B): row 4t+grp, cols j0 + lr*4 ..+3
    const int* ap0 = adj + (size_t)(ib + 0  + grp) * NN + w * 1024 + lr * 4;
    const int* ap1 = adj + (size_t)(ib + 4  + grp) * NN + w * 1024 + lr * 4;
    const int* ap2 = adj + (size_t)(ib + 8  + grp) * NN + w * 1024 + lr * 4;
    const int* ap3 = adj + (size_t)(ib + 12 + grp) * NN + w * 1024 + lr * 4;
    const float* wp = Wh2s + w * 1024 + lr * 4;
    // packed B: chunk c, k-half q, colgroup cg: elem (w*16+c)*4096 + (4q+grp)*512 + cg*128 + lr*8
    const __hip_bfloat16* bq0 = Bpk + (size_t)w * 65536 + (size_t)grp * 512 + lr * 8;
    const __hip_bfloat16* bq1 = bq0 + 2048;

    uint*           Pw = (uint*)(smem + w * 4096);            // word view of wave's P dbuf
    const char*     Pr = smem + w * 4096;                     // byte view for b128 reads

    f32x4 acc0 = {0.f, 0.f, 0.f, 0.f};
    f32x4 acc1 = acc0, acc2 = acc0, acc3 = acc0;
    float lsum0 = 0.f, lsum1 = 0.f, lsum2 = 0.f, lsum3 = 0.f;

    i32x4 va[2][4];
    f32x4 vw[2];
    s16x8 vb[2][8];

#define LD_A(P, C) {                                           \
    va[P][0] = *(const i32x4*)(ap0 + (C) * 64);                \
    va[P][1] = *(const i32x4*)(ap1 + (C) * 64);                \
    va[P][2] = *(const i32x4*)(ap2 + (C) * 64);                \
    va[P][3] = *(const i32x4*)(ap3 + (C) * 64);                \
    vw[P]    = *(const f32x4*)(wp  + (C) * 64); }

#define LD_B(P, C) {                                           \
    _Pragma("unroll")                                          \
    for (int cg = 0; cg < 4; ++cg) {                           \
        vb[P][cg]     = *(const s16x8*)(bq0 + (size_t)(C) * 4096 + cg * 128); \
        vb[P][4 + cg] = *(const s16x8*)(bq1 + (size_t)(C) * 4096 + cg * 128); \
    } }

    // prologue: A(0), B(0), A(1)
    LD_A(0, 0)
    LD_B(0, 0)
    LD_A(1, 1)

    #pragma unroll
    for (int c = 0; c < 16; ++c) {
        const int pc = c & 1, pn = pc ^ 1;

        // (1) issue B(c+1) — BEFORE any new HBM batch
        if (c < 15) LD_B(pn, c + 1)

        // (2) p-compute chunk c from va[pc]/vw[pc]; write wave-private swizzled P
        #pragma unroll
        for (int t = 0; t < 4; ++t) {
            i32x4 av = va[pc][t];
            f32x4 wv = vw[pc];
            float p0, p1, p2, p3;
            {
                float u0 = wh1v[t] + wv[0]; u0 = fmaxf(u0, ALPHA_ * u0);
                float u1 = wh1v[t] + wv[1]; u1 = fmaxf(u1, ALPHA_ * u1);
                float u2 = wh1v[t] + wv[2]; u2 = fmaxf(u2, ALPHA_ * u2);
                float u3 = wh1v[t] + wv[3]; u3 = fmaxf(u3, ALPHA_ * u3);
                p0 = exp2f(u0 - mcsv[t]); p0 = (av[0] != 0) ? p0 : 0.f;
                p1 = exp2f(u1 - mcsv[t]); p1 = (av[1] != 0) ? p1 : 0.f;
                p2 = exp2f(u2 - mcsv[t]); p2 = (av[2] != 0) ? p2 : 0.f;
                p3 = exp2f(u3 - mcsv[t]); p3 = (av[3] != 0) ? p3 : 0.f;
            }
            float ps = (p0 + p1) + (p2 + p3);
            if (t == 0) lsum0 += ps; else if (t == 1) lsum1 += ps;
            else if (t == 2) lsum2 += ps; else lsum3 += ps;
            uint lo = (uint)(unsigned short)f2bf(p0) | ((uint)(unsigned short)f2bf(p1) << 16);
            uint hi = (uint)(unsigned short)f2bf(p2) | ((uint)(unsigned short)f2bf(p3) << 16);
            int r  = 4 * t + grp;
            int su = ((lr >> 1) ^ (r & 7));                   // 16B-unit XOR swizzle
            uint2 pk; pk.x = lo; pk.y = hi;
            *(uint2*)(Pw + pc * 512 + r * 32 + su * 4 + (lr & 1) * 2) = pk;
        }

        // (3) issue adj(c+2) into freed regs (AFTER B(c+1) in program order)
        if (c < 14) LD_A(pc, c + 2)

        // (4) read A-frags (swizzled); lgkmcnt-only wait
        s16x8 a0 = *(const s16x8*)(Pr + pc * 2048 + lr * 128 + ((grp       ^ (lr & 7)) * 16));
        s16x8 a1 = *(const s16x8*)(Pr + pc * 2048 + lr * 128 + (((4 + grp) ^ (lr & 7)) * 16));

        // (5) MFMA with B(c)
        acc0 = MFMA_BF16(a0, vb[pc][0], acc0, 0, 0, 0);
        acc1 = MFMA_BF16(a0, vb[pc][1], acc1, 0, 0, 0);
        acc2 = MFMA_BF16(a0, vb[pc][2], acc2, 0, 0, 0);
        acc3 = MFMA_BF16(a0, vb[pc][3], acc3, 0, 0, 0);
        acc0 = MFMA_BF16(a1, vb[pc][4], acc0, 0, 0, 0);
        acc1 = MFMA_BF16(a1, vb[pc][5], acc1, 0, 0, 0);
        acc2 = MFMA_BF16(a1, vb[pc][6], acc2, 0, 0, 0);
        acc3 = MFMA_BF16(a1, vb[pc][7], acc3, 0, 0, 0);
    }
#undef LD_A
#undef LD_B

    // row-sum partials: reduce over the 16 lanes of each (t, grp) row
    #pragma unroll
    for (int m = 1; m < 16; m <<= 1) {
        lsum0 += __shfl_xor(lsum0, m, 64);
        lsum1 += __shfl_xor(lsum1, m, 64);
        lsum2 += __shfl_xor(lsum2, m, 64);
        lsum3 += __shfl_xor(lsum3, m, 64);
    }

    __syncthreads();   // all waves done with P region before lacc overwrites it

    float (*lacc)[16][65] = (float (*)[16][65])smem;
    float* lls = (float*)(smem + 33280);
    #pragma unroll
    for (int reg = 0; reg < 4; ++reg) {
        int rr = grp * 4 + reg;            // C layout: row=(lane>>4)*4+reg, col=lane&15
        lacc[w][rr][lr]      = acc0[reg];
        lacc[w][rr][16 + lr] = acc1[reg];
        lacc[w][rr][32 + lr] = acc2[reg];
        lacc[w][rr][48 + lr] = acc3[reg];
    }
    if (lr == 0) {
        lls[w * 16 + grp]      = lsum0;
        lls[w * 16 + 4 + grp]  = lsum1;
        lls[w * 16 + 8 + grp]  = lsum2;
        lls[w * 16 + 12 + grp] = lsum3;
    }
    __syncthreads();

    #pragma unroll
    for (int t = 0; t < 2; ++t) {
        int idx = tid + t * 512;           // 1024 outputs: 16 rows x 64 cols
        int rr = idx >> 6, cc = idx & 63;
        float v = 0.f, ls = 0.f;
        #pragma unroll
        for (int ww = 0; ww < 8; ++ww) {
            v += lacc[ww][rr][cc];
            ls += lls[ww * 16 + rr];
        }
        float hv = v / ls;
        out[(size_t)(ib + rr) * OUTD + cc] = hv > 0.f ? hv : exp2f(hv * LOG2E) - 1.f;
    }
}

extern "C" void kernel_launch(void* const* d_in, const int* in_sizes, int n_in,
                              void* d_out, int out_size, void* d_ws, size_t ws_size,
                              hipStream_t stream) {
    const float* h   = (const float*)d_in[0];
    const int*   adj = (const int*)d_in[1];
    const float* W   = (const float*)d_in[2];
    const float* a   = (const float*)d_in[3];
    float* out = (float*)d_out;

    char* ws = (char*)d_ws;
    __hip_bfloat16*  Bpk  = (__hip_bfloat16*)ws;                     // 1 MB
    float*           Wh1s = (float*)(ws + 1048576);                  // 32 KB
    float*           Wh2s = Wh1s + NN;                               // 32 KB
    uint*            mxk  = (uint*)(Wh2s + NN);                      // 4 B

    hipMemsetAsync(mxk, 0, 4, stream);     // encoded -inf identity (all encodings > 0)
    k_wh<<<NN / 8, 256, 0, stream>>>(h, W, a, (uint*)Bpk, Wh1s, Wh2s, mxk);
    k_gat<<<NN / 16, 512, 0, stream>>>(adj, Bpk, Wh1s, Wh2s, mxk, out);
}

// Round 11
// 142.736 us; speedup vs baseline: 1.4156x; 1.0732x over previous
//
#include <hip/hip_runtime.h>
#include <hip/hip_bf16.h>

#define NN 8192
#define IND 512
#define OUTD 64
#define ALPHA_ 0.2f
#define LOG2E 1.4426950408889634f

typedef float f32x4 __attribute__((ext_vector_type(4)));
typedef short s16x8 __attribute__((ext_vector_type(8)));
typedef int   i32x4 __attribute__((ext_vector_type(4)));
typedef unsigned int uint;

static __device__ __forceinline__ short f2bf(float x) {
    __hip_bfloat16 b = __float2bfloat16(x);
    return *reinterpret_cast<short*>(&b);
}
static __device__ __forceinline__ uint fenc(float f) {
    uint u = __float_as_uint(f);
    return (u & 0x80000000u) ? ~u : (u | 0x80000000u);
}
static __device__ __forceinline__ float fdec(uint k) {
    uint u = (k & 0x80000000u) ? (k & 0x7FFFFFFFu) : ~k;
    return __uint_as_float(u);
}

// ---- kernel 1: Wh = h@W; writes B-fragment-packed panel Bpk (bf16, 1MB):
//      elem ((o*4+cg)*16+lr)*8 + e  =  Wh[8o+e][16cg+lr]
//      Also Wh1s/Wh2s prescaled by log2e, and global max via atomicMax. ----
__global__ __launch_bounds__(256) void k_wh(const float* __restrict__ h,
                                            const float* __restrict__ W,
                                            const float* __restrict__ a,
                                            uint* __restrict__ Bpk32,
                                            float* __restrict__ Wh1s,
                                            float* __restrict__ Wh2s,
                                            uint* __restrict__ mxk) {
    __shared__ float hs[8 * IND];      // 16 KB
    int tid = threadIdx.x;
    const f32x4* h4 = (const f32x4*)(h + (size_t)blockIdx.x * 8 * IND);
    f32x4* hs4 = (f32x4*)hs;
    #pragma unroll
    for (int t = 0; t < 4; ++t) hs4[tid + t * 256] = h4[tid + t * 256];
    __syncthreads();

    int w = tid >> 6, l = tid & 63;
    int g = l >> 4, lc = l & 15;
    int c4 = lc * 4;
    const float* hrow = hs + (w * 2) * IND;
    f32x4 acc0 = {0.f, 0.f, 0.f, 0.f};
    f32x4 acc1 = {0.f, 0.f, 0.f, 0.f};

    #pragma unroll 4
    for (int k0 = 0; k0 < 128; ++k0) {
        int k = k0 * 4 + g;
        f32x4 wv = *(const f32x4*)(W + k * OUTD + c4);
        float h0 = hrow[k];
        float h1 = hrow[IND + k];
        acc0[0] = fmaf(h0, wv[0], acc0[0]);
        acc0[1] = fmaf(h0, wv[1], acc0[1]);
        acc0[2] = fmaf(h0, wv[2], acc0[2]);
        acc0[3] = fmaf(h0, wv[3], acc0[3]);
        acc1[0] = fmaf(h1, wv[0], acc1[0]);
        acc1[1] = fmaf(h1, wv[1], acc1[1]);
        acc1[2] = fmaf(h1, wv[2], acc1[2]);
        acc1[3] = fmaf(h1, wv[3], acc1[3]);
    }

    #pragma unroll
    for (int e = 0; e < 4; ++e) {
        acc0[e] += __shfl_xor(acc0[e], 16, 64);
        acc0[e] += __shfl_xor(acc0[e], 32, 64);
        acc1[e] += __shfl_xor(acc1[e], 16, 64);
        acc1[e] += __shfl_xor(acc1[e], 32, 64);
    }

    int row0 = blockIdx.x * 8 + w * 2;     // even; rows row0, row0+1
    if (g == 0) {
        int o = row0 >> 3, e2 = (row0 & 7) >> 1;
        #pragma unroll
        for (int ee = 0; ee < 4; ++ee) {
            int col = c4 + ee, cg = col >> 4, lrr = col & 15;
            uint lo = (uint)(unsigned short)f2bf(acc0[ee]);
            uint hi = (uint)(unsigned short)f2bf(acc1[ee]);
            Bpk32[((o * 4 + cg) * 16 + lrr) * 4 + e2] = lo | (hi << 16);
        }
    }

    float p10 = 0.f, p20 = 0.f, p11 = 0.f, p21 = 0.f;
    #pragma unroll
    for (int e = 0; e < 4; ++e) {
        float a1 = a[c4 + e], a2 = a[OUTD + c4 + e];
        p10 = fmaf(acc0[e], a1, p10);
        p20 = fmaf(acc0[e], a2, p20);
        p11 = fmaf(acc1[e], a1, p11);
        p21 = fmaf(acc1[e], a2, p21);
    }
    #pragma unroll
    for (int off = 1; off < 16; off <<= 1) {
        p10 += __shfl_xor(p10, off, 64);
        p20 += __shfl_xor(p20, off, 64);
        p11 += __shfl_xor(p11, off, 64);
        p21 += __shfl_xor(p21, off, 64);
    }
    if (l == 0) {
        float s20 = p20 * LOG2E, s21 = p21 * LOG2E;
        Wh1s[row0]     = p10 * LOG2E;  Wh2s[row0]     = s20;
        Wh1s[row0 + 1] = p11 * LOG2E;  Wh2s[row0 + 1] = s21;
        atomicMax(mxk, fenc(fmaxf(s20, s21)));
    }
}

#define MFMA_BF16 __builtin_amdgcn_mfma_f32_16x16x32_bf16

// ---- kernel 2: fused mask+softmax+PV. R9 structure (reg-built A-frags, no LDS
// in loop), with the latency fix: B(L2) issued BEFORE adj(HBM) in program order
// (in-order vmcnt retire -> MFMAs never drain an HBM load), and adj prefetched
// at distance 2 via unroll-2 with two named register sets (X even / Y odd). ----
__global__ __launch_bounds__(512) void k_gat(const int* __restrict__ adj,
                                             const __hip_bfloat16* __restrict__ Bpk,
                                             const float* __restrict__ Wh1s,
                                             const float* __restrict__ Wh2s,
                                             const uint* __restrict__ mxk,
                                             float* __restrict__ out) {
    int tid = threadIdx.x;
    int w   = tid >> 6;        // wave 0..7
    int l   = tid & 63;
    int lr  = l & 15;
    int grp = l >> 4;
    int ib  = blockIdx.x * 16;
    int row = ib + lr;

    float wh1s = Wh1s[row];
    float t0 = wh1s + fdec(*mxk);          // upper bound (scaled domain; leakyrelu monotone)
    float mcs = fmaxf(t0, ALPHA_ * t0);

    const int* ap = adj + (size_t)row * NN;
    int jbase = w * 32 + grp * 8;
    // packed B pointer: elem ((w*4+grp)*4+cg)*128 + lr*8 ; iter stride 16384 elems
    const __hip_bfloat16* bb = Bpk + (size_t)(w * 4 + grp) * 512 + lr * 8;

    f32x4 acc0 = {0.f, 0.f, 0.f, 0.f};
    f32x4 acc1 = acc0, acc2 = acc0, acc3 = acc0;
    float lsum = 0.f;

    // register sets
    i32x4 xa0, xa1;  f32x4 xw0, xw1;      // adj set X (even iters), distance 2
    i32x4 ya0, ya1;  f32x4 yw0, yw1;      // adj set Y (odd iters),  distance 2
    s16x8 pb0, pb1, pb2, pb3;             // B set P (even iters),   distance 1
    s16x8 qb0, qb1, qb2, qb3;             // B set Q (odd iters),    distance 1

#define LDA(A0, A1, W0, W1, IT) {                              \
    int jl_ = (IT) * 256 + jbase;                              \
    A0 = *(const i32x4*)(ap + jl_);                            \
    A1 = *(const i32x4*)(ap + jl_ + 4);                        \
    W0 = *(const f32x4*)(Wh2s + jl_);                          \
    W1 = *(const f32x4*)(Wh2s + jl_ + 4); }

#define LDB(B0, B1, B2, B3, IT) {                              \
    size_t bo_ = (size_t)(IT) * 16384;                         \
    B0 = *(const s16x8*)(bb + bo_);                            \
    B1 = *(const s16x8*)(bb + bo_ + 128);                      \
    B2 = *(const s16x8*)(bb + bo_ + 256);                      \
    B3 = *(const s16x8*)(bb + bo_ + 384); }

#define PCOMP(A0, A1, W0, W1, AF) {                            \
    _Pragma("unroll")                                          \
    for (int e = 0; e < 4; ++e) {                              \
        float t_ = wh1s + (W0)[e];                             \
        float x_ = fmaxf(t_, ALPHA_ * t_);                     \
        float p_ = exp2f(x_ - mcs);                            \
        p_ = ((A0)[e] != 0) ? p_ : 0.f;                        \
        lsum += p_; (AF)[e] = f2bf(p_);                        \
    }                                                          \
    _Pragma("unroll")                                          \
    for (int e = 0; e < 4; ++e) {                              \
        float t_ = wh1s + (W1)[e];                             \
        float x_ = fmaxf(t_, ALPHA_ * t_);                     \
        float p_ = exp2f(x_ - mcs);                            \
        p_ = ((A1)[e] != 0) ? p_ : 0.f;                        \
        lsum += p_; (AF)[e + 4] = f2bf(p_);                    \
    } }

    // prologue: B(0) first (L2), then adj(0), adj(1)
    LDB(pb0, pb1, pb2, pb3, 0)
    LDA(xa0, xa1, xw0, xw1, 0)
    LDA(ya0, ya1, yw0, yw1, 1)

    for (int it2 = 0; it2 < 16; ++it2) {
        int c0 = 2 * it2, c1 = c0 + 1;
        // ---- even iter c0: consume X + P ----
        LDB(qb0, qb1, qb2, qb3, c1)              // B(c0+1): L2, issued FIRST
        s16x8 afx;
        PCOMP(xa0, xa1, xw0, xw1, afx)           // consume X(c0) (HBM, 2 iters old)
        if (c0 + 2 < 32) LDA(xa0, xa1, xw0, xw1, c0 + 2)   // refill X at distance 2
        acc0 = MFMA_BF16(afx, pb0, acc0, 0, 0, 0);
        acc1 = MFMA_BF16(afx, pb1, acc1, 0, 0, 0);
        acc2 = MFMA_BF16(afx, pb2, acc2, 0, 0, 0);
        acc3 = MFMA_BF16(afx, pb3, acc3, 0, 0, 0);
        // ---- odd iter c1: consume Y + Q ----
        if (c1 + 1 < 32) LDB(pb0, pb1, pb2, pb3, c1 + 1)   // B(c1+1): L2, FIRST
        s16x8 afy;
        PCOMP(ya0, ya1, yw0, yw1, afy)           // consume Y(c1)
        if (c1 + 2 < 32) LDA(ya0, ya1, yw0, yw1, c1 + 2)   // refill Y at distance 2
        acc0 = MFMA_BF16(afy, qb0, acc0, 0, 0, 0);
        acc1 = MFMA_BF16(afy, qb1, acc1, 0, 0, 0);
        acc2 = MFMA_BF16(afy, qb2, acc2, 0, 0, 0);
        acc3 = MFMA_BF16(afy, qb3, acc3, 0, 0, 0);
    }
#undef LDA
#undef LDB
#undef PCOMP

    // denominator: sum across the 4 k-groups (lanes xor 16/32)
    lsum += __shfl_xor(lsum, 16, 64);
    lsum += __shfl_xor(lsum, 32, 64);

    // cross-wave combine via LDS
    __shared__ float lacc[8][16][65];
    __shared__ float lls[8][16];
    #pragma unroll
    for (int reg = 0; reg < 4; ++reg) {
        int rr = grp * 4 + reg;            // C layout: row=(lane>>4)*4+reg, col=lane&15
        lacc[w][rr][lr]      = acc0[reg];
        lacc[w][rr][16 + lr] = acc1[reg];
        lacc[w][rr][32 + lr] = acc2[reg];
        lacc[w][rr][48 + lr] = acc3[reg];
    }
    if (l < 16) lls[w][l] = lsum;
    __syncthreads();

    #pragma unroll
    for (int t = 0; t < 2; ++t) {
        int idx = tid + t * 512;           // 1024 outputs: 16 rows x 64 cols
        int rr = idx >> 6, c = idx & 63;
        float v = 0.f, ls = 0.f;
        #pragma unroll
        for (int ww = 0; ww < 8; ++ww) {
            v += lacc[ww][rr][c];
            ls += lls[ww][rr];
        }
        float hv = v / ls;
        out[(size_t)(ib + rr) * OUTD + c] = hv > 0.f ? hv : exp2f(hv * LOG2E) - 1.f;
    }
}

extern "C" void kernel_launch(void* const* d_in, const int* in_sizes, int n_in,
                              void* d_out, int out_size, void* d_ws, size_t ws_size,
                              hipStream_t stream) {
    const float* h   = (const float*)d_in[0];
    const int*   adj = (const int*)d_in[1];
    const float* W   = (const float*)d_in[2];
    const float* a   = (const float*)d_in[3];
    float* out = (float*)d_out;

    char* ws = (char*)d_ws;
    __hip_bfloat16*  Bpk  = (__hip_bfloat16*)ws;                     // 1 MB
    float*           Wh1s = (float*)(ws + 1048576);                  // 32 KB
    float*           Wh2s = Wh1s + NN;                               // 32 KB
    uint*            mxk  = (uint*)(Wh2s + NN);                      // 4 B

    hipMemsetAsync(mxk, 0, 4, stream);     // encoded -inf identity (all encodings > 0)
    k_wh<<<NN / 8, 256, 0, stream>>>(h, W, a, (uint*)Bpk, Wh1s, Wh2s, mxk);
    k_gat<<<NN / 16, 512, 0, stream>>>(adj, Bpk, Wh1s, Wh2s, mxk, out);
}